// Round 8
// baseline (923.224 us; speedup 1.0000x reference)
//
#include <hip/hip_runtime.h>

#define N_NODES  100000
#define N_EDGES  1600000
#define N_GRAPHS 2000
#define F_IN     32
#define H        64
#define N_LAYERS 5
#define LN_EPS   1e-5f

#define SCAN_BLK 512
#define SCAN_EPB 2048                                  // 4 elems/thread
#define SCAN_NB  ((N_NODES + SCAN_EPB - 1) / SCAN_EPB) // 49 blocks

typedef unsigned short u16;
typedef int i4 __attribute__((ext_vector_type(4)));    // clang vector type

__device__ __forceinline__ float bf2f(u16 v) {
    union { unsigned u; float f; } c; c.u = ((unsigned)v) << 16; return c.f;
}
__device__ __forceinline__ u16 f2bf(float f) {   // round-to-nearest-even
    union { float f; unsigned u; } c; c.f = f;
    return (u16)((c.u + 0x7fffu + ((c.u >> 16) & 1u)) >> 16);
}

// ---------------- CSR build: histogram of dst (int4-vectorized) ----------------
__global__ __launch_bounds__(256) void k_hist(const int* __restrict__ ei,
                                              int* __restrict__ cnt)
{
    const int4* d4 = reinterpret_cast<const int4*>(ei + N_EDGES);
    int i = blockIdx.x * 256 + threadIdx.x;
    int stride = gridDim.x * 256;
    for (int e = i; e < N_EDGES / 4; e += stride) {
        int4 d = d4[e];
        atomicAdd(&cnt[d.x], 1);
        atomicAdd(&cnt[d.y], 1);
        atomicAdd(&cnt[d.z], 1);
        atomicAdd(&cnt[d.w], 1);
    }
}

// ---- CSR build: exclusive scan over PADDED counts (ceil(cnt/4)*4) ----
__global__ __launch_bounds__(SCAN_BLK) void k_scan1(const int* __restrict__ cnt,
                                                    int* __restrict__ rp,
                                                    int* __restrict__ bsum)
{
    __shared__ int s[SCAN_BLK];
    int tid = threadIdx.x;
    int base = blockIdx.x * SCAN_EPB + tid * 4;
    int v0 = (base + 0 < N_NODES) ? ((cnt[base + 0] + 3) & ~3) : 0;
    int v1 = (base + 1 < N_NODES) ? ((cnt[base + 1] + 3) & ~3) : 0;
    int v2 = (base + 2 < N_NODES) ? ((cnt[base + 2] + 3) & ~3) : 0;
    int v3 = (base + 3 < N_NODES) ? ((cnt[base + 3] + 3) & ~3) : 0;
    int tsum = v0 + v1 + v2 + v3;
    s[tid] = tsum;
    __syncthreads();
    for (int off = 1; off < SCAN_BLK; off <<= 1) {
        int t = (tid >= off) ? s[tid - off] : 0;
        __syncthreads();
        s[tid] += t;
        __syncthreads();
    }
    int excl = s[tid] - tsum;
    if (base + 0 < N_NODES) rp[base + 0] = excl;
    if (base + 1 < N_NODES) rp[base + 1] = excl + v0;
    if (base + 2 < N_NODES) rp[base + 2] = excl + v0 + v1;
    if (base + 3 < N_NODES) rp[base + 3] = excl + v0 + v1 + v2;
    if (tid == SCAN_BLK - 1) bsum[blockIdx.x] = s[tid];
}

__global__ void k_scan2(int* __restrict__ bsum, int* __restrict__ rp)
{
    if (threadIdx.x == 0 && blockIdx.x == 0) {
        int acc = 0;
        for (int b = 0; b < SCAN_NB; ++b) { int t = bsum[b]; bsum[b] = acc; acc += t; }
        rp[N_NODES] = acc;   // total padded edge slots
    }
}

__global__ __launch_bounds__(SCAN_BLK) void k_scan3(int* __restrict__ rp,
                                                    const int* __restrict__ bsum,
                                                    int* __restrict__ cursor)
{
    int tid = threadIdx.x, blk = blockIdx.x;
    int add = bsum[blk];
    int base = blk * SCAN_EPB + tid * 4;
    #pragma unroll
    for (int i = 0; i < 4; ++i) {
        int idx = base + i;
        if (idx < N_NODES) { int v = rp[idx] + add; rp[idx] = v; cursor[idx] = v; }
    }
}

// ---- CSR build: zero-fill pad slots (mult=0); plain stores so L2 merges lines ----
__global__ __launch_bounds__(256) void k_padfill(const int* __restrict__ rp,
                                                 const int* __restrict__ cnt,
                                                 i4* __restrict__ erec)
{
    int n = blockIdx.x * 256 + threadIdx.x;
    if (n >= N_NODES) return;
    int s = rp[n] + cnt[n], e = rp[n + 1];
    i4 z = (i4){0, 0, 0, 0};
    for (int p = s; p < e; ++p) erec[p] = z;
}

// -- CSR build: scatter 16B records {src*16, bf16x2, bf16x2, mult=1.0f}, 4 edges/thread --
// Plain stores: dst-sorted slots are adjacent, L2 write-merges partial lines.
__global__ __launch_bounds__(256) void k_scatter(const int* __restrict__ ei,
                                                 const float* __restrict__ ea,
                                                 int* __restrict__ cursor,
                                                 i4* __restrict__ erec)
{
    const int4* s4 = reinterpret_cast<const int4*>(ei);
    const int4* d4 = reinterpret_cast<const int4*>(ei + N_EDGES);
    const float4* a4 = reinterpret_cast<const float4*>(ea);
    const int one = 0x3f800000;   // 1.0f bits
    int i = blockIdx.x * 256 + threadIdx.x;
    int stride = gridDim.x * 256;
    for (int e = i; e < N_EDGES / 4; e += stride) {
        int4 s = s4[e];
        int4 d = d4[e];
        float4 a0 = a4[e * 4 + 0], a1 = a4[e * 4 + 1];
        float4 a2 = a4[e * 4 + 2], a3 = a4[e * 4 + 3];
        int p0 = atomicAdd(&cursor[d.x], 1);
        int p1 = atomicAdd(&cursor[d.y], 1);
        int p2 = atomicAdd(&cursor[d.z], 1);
        int p3 = atomicAdd(&cursor[d.w], 1);
        erec[p0] = (i4){ s.x * 16,
            (int)((unsigned)f2bf(a0.x) | ((unsigned)f2bf(a0.y) << 16)),
            (int)((unsigned)f2bf(a0.z) | ((unsigned)f2bf(a0.w) << 16)), one };
        erec[p1] = (i4){ s.y * 16,
            (int)((unsigned)f2bf(a1.x) | ((unsigned)f2bf(a1.y) << 16)),
            (int)((unsigned)f2bf(a1.z) | ((unsigned)f2bf(a1.w) << 16)), one };
        erec[p2] = (i4){ s.z * 16,
            (int)((unsigned)f2bf(a2.x) | ((unsigned)f2bf(a2.y) << 16)),
            (int)((unsigned)f2bf(a2.z) | ((unsigned)f2bf(a2.w) << 16)), one };
        erec[p3] = (i4){ s.w * 16,
            (int)((unsigned)f2bf(a3.x) | ((unsigned)f2bf(a3.y) << 16)),
            (int)((unsigned)f2bf(a3.z) | ((unsigned)f2bf(a3.w) << 16)), one };
    }
}

// -------- graph rowptr from sorted batch (boundary detect, no atomics) --------
__global__ __launch_bounds__(256) void k_gptr(const int* __restrict__ batch,
                                              int* __restrict__ gp)
{
    int n = blockIdx.x * 256 + threadIdx.x;
    if (n >= N_NODES) return;
    int b  = batch[n];
    int bp = (n == 0) ? -1 : batch[n - 1];
    for (int g = bp + 1; g <= b; ++g) gp[g] = n;
    if (n == N_NODES - 1)
        for (int g = b + 1; g <= N_GRAPHS; ++g) gp[g] = N_NODES;
}

// ---------------- input projection: h = relu(x @ W_in + b_in) -> bf16 ----------------
__global__ __launch_bounds__(256) void k_input_proj(
        const float* __restrict__ x, const float* __restrict__ Win,
        const float* __restrict__ bin, u16* __restrict__ h)
{
    __shared__ float Ws[F_IN * H];
    __shared__ float bs[H];
    int tid = threadIdx.x;
    for (int i = tid; i < F_IN * H; i += 256) Ws[i] = Win[i];
    if (tid < H) bs[tid] = bin[tid];
    __syncthreads();
    int lane = tid & 63;
    int wid  = tid >> 6;
    for (int n = blockIdx.x * 4 + wid; n < N_NODES; n += gridDim.x * 4) {
        const float* xr = x + (size_t)n * F_IN;
        float acc = bs[lane];
        #pragma unroll
        for (int k = 0; k < F_IN; ++k)
            acc = fmaf(xr[k], Ws[k * H + lane], acc);
        h[(size_t)n * H + lane] = f2bf(fmaxf(acc, 0.f));
    }
}

// ---- fused layer: z = h + sum_in relu(h[src]+e@We+be); h' = relu(mlp(z)) ----
// Phase 1: 16-lane groups, quad body + next-quad erec prefetch (8 loads in flight).
// Phase 2: tiled 64x64 MLP on LDS z tile.
__global__ __launch_bounds__(256, 6) void k_layer(
        const int* __restrict__ rp, const i4* __restrict__ erec,
        const float* __restrict__ We_l, const float* __restrict__ be_l,
        const float* __restrict__ W1l, const float* __restrict__ b1l,
        const float* __restrict__ W2l, const float* __restrict__ b2l,
        const u16* __restrict__ hin, u16* __restrict__ hout)
{
    __shared__ float zs[64][65];
    int tid  = threadIdx.x;
    int lane = tid & 63, w = tid >> 6;
    int q = lane >> 4, r = lane & 15;     // group q in [0,4), lane-in-group r
    int n0 = blockIdx.x * 64;
    const ushort4* hin4 = reinterpret_cast<const ushort4*>(hin);

    // per-lane: We columns 4r..4r+3 (4 attr rows) + bias
    float4 wr0 = *reinterpret_cast<const float4*>(We_l + 0 * H + r * 4);
    float4 wr1 = *reinterpret_cast<const float4*>(We_l + 1 * H + r * 4);
    float4 wr2 = *reinterpret_cast<const float4*>(We_l + 2 * H + r * 4);
    float4 wr3 = *reinterpret_cast<const float4*>(We_l + 3 * H + r * 4);
    float4 bv  = *reinterpret_cast<const float4*>(be_l + r * 4);

    for (int t = 0; t < 4; ++t) {
        int row = w * 16 + t * 4 + q;
        int n   = n0 + row;
        float4 acc = make_float4(0.f, 0.f, 0.f, 0.f);
        if (n < N_NODES) {
            ushort4 hs = hin4[(unsigned)n * 16 + r];     // self term (eps=0)
            acc.x = bf2f(hs.x); acc.y = bf2f(hs.y);
            acc.z = bf2f(hs.z); acc.w = bf2f(hs.w);
            int j0 = rp[n], j1 = rp[n + 1];              // padded to multiple of 4
            if (j0 < j1) {
                i4 R[4], P[4];
                #pragma unroll
                for (int k = 0; k < 4; ++k)
                    R[k] = __builtin_nontemporal_load(&erec[j0 + k]);
                for (int j = j0; j < j1; j += 4) {
                    // prefetch next quad (tail slack in erec makes j+4..j+7 safe)
                    #pragma unroll
                    for (int k = 0; k < 4; ++k)
                        P[k] = __builtin_nontemporal_load(&erec[j + 4 + k]);
                    ushort4 G[4];
                    #pragma unroll
                    for (int k = 0; k < 4; ++k)
                        G[k] = hin4[(unsigned)R[k].x + r];   // R.x = src*16
                    #pragma unroll
                    for (int k = 0; k < 4; ++k) {
                        float mult = __int_as_float(R[k].w);
                        float ax = bf2f((u16)(R[k].y & 0xffff));
                        float ay = bf2f((u16)(((unsigned)R[k].y) >> 16));
                        float az = bf2f((u16)(R[k].z & 0xffff));
                        float aw = bf2f((u16)(((unsigned)R[k].z) >> 16));
                        float e0 = fmaf(ax, wr0.x, fmaf(ay, wr1.x, fmaf(az, wr2.x, fmaf(aw, wr3.x, bv.x))));
                        float e1 = fmaf(ax, wr0.y, fmaf(ay, wr1.y, fmaf(az, wr2.y, fmaf(aw, wr3.y, bv.y))));
                        float e2 = fmaf(ax, wr0.z, fmaf(ay, wr1.z, fmaf(az, wr2.z, fmaf(aw, wr3.z, bv.z))));
                        float e3 = fmaf(ax, wr0.w, fmaf(ay, wr1.w, fmaf(az, wr2.w, fmaf(aw, wr3.w, bv.w))));
                        acc.x = fmaf(mult, fmaxf(bf2f(G[k].x) + e0, 0.f), acc.x);
                        acc.y = fmaf(mult, fmaxf(bf2f(G[k].y) + e1, 0.f), acc.y);
                        acc.z = fmaf(mult, fmaxf(bf2f(G[k].z) + e2, 0.f), acc.z);
                        acc.w = fmaf(mult, fmaxf(bf2f(G[k].w) + e3, 0.f), acc.w);
                    }
                    #pragma unroll
                    for (int k = 0; k < 4; ++k) R[k] = P[k];
                }
            }
        }
        zs[row][r * 4 + 0] = acc.x;
        zs[row][r * 4 + 1] = acc.y;
        zs[row][r * 4 + 2] = acc.z;
        zs[row][r * 4 + 3] = acc.w;
    }
    __syncthreads();

    // phase 2: MLP on the 64x64 tile
    int tr = (tid >> 4) * 4, tc = (tid & 15) * 4;
    float a1[4][4];
    #pragma unroll
    for (int i = 0; i < 4; ++i)
        #pragma unroll
        for (int j = 0; j < 4; ++j) a1[i][j] = b1l[tc + j];
    #pragma unroll 8
    for (int k = 0; k < H; ++k) {
        float4 wv = *reinterpret_cast<const float4*>(&W1l[k * H + tc]);
        #pragma unroll
        for (int i = 0; i < 4; ++i) {
            float zr = zs[tr + i][k];
            a1[i][0] = fmaf(zr, wv.x, a1[i][0]);
            a1[i][1] = fmaf(zr, wv.y, a1[i][1]);
            a1[i][2] = fmaf(zr, wv.z, a1[i][2]);
            a1[i][3] = fmaf(zr, wv.w, a1[i][3]);
        }
    }
    __syncthreads();
    #pragma unroll
    for (int i = 0; i < 4; ++i)
        #pragma unroll
        for (int j = 0; j < 4; ++j) zs[tr + i][tc + j] = fmaxf(a1[i][j], 0.f);
    __syncthreads();

    float a2[4][4];
    #pragma unroll
    for (int i = 0; i < 4; ++i)
        #pragma unroll
        for (int j = 0; j < 4; ++j) a2[i][j] = b2l[tc + j];
    #pragma unroll 8
    for (int k = 0; k < H; ++k) {
        float4 wv = *reinterpret_cast<const float4*>(&W2l[k * H + tc]);
        #pragma unroll
        for (int i = 0; i < 4; ++i) {
            float zr = zs[tr + i][k];
            a2[i][0] = fmaf(zr, wv.x, a2[i][0]);
            a2[i][1] = fmaf(zr, wv.y, a2[i][1]);
            a2[i][2] = fmaf(zr, wv.z, a2[i][2]);
            a2[i][3] = fmaf(zr, wv.w, a2[i][3]);
        }
    }
    #pragma unroll
    for (int i = 0; i < 4; ++i) {
        int n = n0 + tr + i;
        if (n < N_NODES) {
            ushort4 o;
            o.x = f2bf(fmaxf(a2[i][0], 0.f));
            o.y = f2bf(fmaxf(a2[i][1], 0.f));
            o.z = f2bf(fmaxf(a2[i][2], 0.f));
            o.w = f2bf(fmaxf(a2[i][3], 0.f));
            *reinterpret_cast<ushort4*>(&hout[(size_t)n * H + tc]) = o;
        }
    }
}

// ------- fused pool + LN + head: one wave per graph (batch sorted -> rowptr) -------
__global__ __launch_bounds__(64) void k_poolfinal(
        const u16* __restrict__ hb, const int* __restrict__ gp,
        const float* __restrict__ Wout, const float* __restrict__ bout,
        float* __restrict__ out)
{
    int g = blockIdx.x, lane = threadIdx.x;
    int a = gp[g], b = gp[g + 1];
    float s0 = 0.f, s1 = 0.f;
    int n = a;
    for (; n + 1 < b; n += 2) {
        s0 += bf2f(hb[(size_t)n * H + lane]);
        s1 += bf2f(hb[(size_t)(n + 1) * H + lane]);
    }
    if (n < b) s0 += bf2f(hb[(size_t)n * H + lane]);
    float v = (s0 + s1) / fmaxf((float)(b - a), 1.f);
    float t = v;
    #pragma unroll
    for (int off = 32; off; off >>= 1) t += __shfl_xor(t, off);
    float mu = t * (1.0f / H);
    float d  = v - mu;
    float s2 = d * d;
    #pragma unroll
    for (int off = 32; off; off >>= 1) s2 += __shfl_xor(s2, off);
    float var = s2 * (1.0f / H);
    float y = d * rsqrtf(var + LN_EPS);
    float p = y * Wout[lane];
    #pragma unroll
    for (int off = 32; off; off >>= 1) p += __shfl_xor(p, off);
    if (lane == 0) out[g] = p + bout[0];
}

extern "C" void kernel_launch(void* const* d_in, const int* in_sizes, int n_in,
                              void* d_out, int out_size, void* d_ws, size_t ws_size,
                              hipStream_t stream)
{
    const float* x     = (const float*)d_in[0];
    const int*   ei    = (const int*)  d_in[1];
    const float* ea    = (const float*)d_in[2];
    const int*   batch = (const int*)  d_in[3];
    const float* Win   = (const float*)d_in[4];
    const float* bin   = (const float*)d_in[5];
    const float* We    = (const float*)d_in[6];
    const float* be    = (const float*)d_in[7];
    const float* W1    = (const float*)d_in[8];
    const float* b1    = (const float*)d_in[9];
    const float* W2    = (const float*)d_in[10];
    const float* b2    = (const float*)d_in[11];
    const float* Wout  = (const float*)d_in[12];
    const float* bout  = (const float*)d_in[13];
    float* out = (float*)d_out;

    char* ws = (char*)d_ws;
    size_t off = 0;
    auto alloc = [&](size_t bytes) -> char* {
        char* p = ws + off;
        off += (bytes + 255) & ~(size_t)255;
        return p;
    };
    const size_t HBH   = (size_t)N_NODES * H * sizeof(u16);              // 12.8 MB
    const size_t NEPAD = (size_t)N_EDGES + 3 * (size_t)N_NODES + 64;     // padded capacity + tail slack
    u16*  h0     = (u16*) alloc(HBH);
    u16*  h1     = (u16*) alloc(HBH);
    i4*   erec   = (i4*)  alloc(NEPAD * sizeof(i4));                     // ~30.4 MB
    int*  cnt    = (int*) alloc((size_t)N_NODES * sizeof(int));
    int*  rp     = (int*) alloc((size_t)(N_NODES + 1) * sizeof(int));
    int*  cursor = (int*) alloc((size_t)N_NODES * sizeof(int));
    int*  bsum   = (int*) alloc((size_t)SCAN_NB * sizeof(int));
    int*  gp     = (int*) alloc((size_t)(N_GRAPHS + 1) * sizeof(int));

    // ---- CSR build (dst-sorted padded edge records, attrs bf16, src pre-scaled) ----
    (void)hipMemsetAsync(cnt, 0, (size_t)N_NODES * sizeof(int), stream);
    k_hist<<<1600, 256, 0, stream>>>(ei, cnt);
    k_scan1<<<SCAN_NB, SCAN_BLK, 0, stream>>>(cnt, rp, bsum);
    k_scan2<<<1, 64, 0, stream>>>(bsum, rp);
    k_scan3<<<SCAN_NB, SCAN_BLK, 0, stream>>>(rp, bsum, cursor);
    k_padfill<<<(N_NODES + 255) / 256, 256, 0, stream>>>(rp, cnt, erec);
    k_scatter<<<1600, 256, 0, stream>>>(ei, ea, cursor, erec);
    k_gptr<<<(N_NODES + 255) / 256, 256, 0, stream>>>(batch, gp);

    // ---- network ----
    k_input_proj<<<1024, 256, 0, stream>>>(x, Win, bin, h0);
    u16* cur = h0;
    u16* nxt = h1;
    const int NBLK = (N_NODES + 63) / 64;
    for (int l = 0; l < N_LAYERS; ++l) {
        k_layer<<<NBLK, 256, 0, stream>>>(rp, erec,
                We + (size_t)l * 4 * H, be + (size_t)l * H,
                W1 + (size_t)l * H * H, b1 + (size_t)l * H,
                W2 + (size_t)l * H * H, b2 + (size_t)l * H,
                cur, nxt);
        u16* t = cur; cur = nxt; nxt = t;
    }

    k_poolfinal<<<N_GRAPHS, 64, 0, stream>>>(cur, gp, Wout, bout, out);
}

// Round 9
// 766.146 us; speedup vs baseline: 1.2050x; 1.2050x over previous
//
#include <hip/hip_runtime.h>

#define N_NODES  100000
#define N_EDGES  1600000
#define N_GRAPHS 2000
#define F_IN     32
#define H        64
#define N_LAYERS 5
#define LN_EPS   1e-5f

#define SCAN_BLK 512
#define SCAN_EPB 2048                                  // 4 elems/thread
#define SCAN_NB  ((N_NODES + SCAN_EPB - 1) / SCAN_EPB) // 49 blocks

typedef unsigned short u16;
typedef int i4 __attribute__((ext_vector_type(4)));    // clang vector type

__device__ __forceinline__ float bf2f(u16 v) {
    union { unsigned u; float f; } c; c.u = ((unsigned)v) << 16; return c.f;
}
__device__ __forceinline__ u16 f2bf(float f) {   // round-to-nearest-even
    union { float f; unsigned u; } c; c.f = f;
    return (u16)((c.u + 0x7fffu + ((c.u >> 16) & 1u)) >> 16);
}

// ---------------- CSR build: histogram of dst (int4-vectorized) ----------------
__global__ __launch_bounds__(256) void k_hist(const int* __restrict__ ei,
                                              int* __restrict__ cnt)
{
    const int4* d4 = reinterpret_cast<const int4*>(ei + N_EDGES);
    int i = blockIdx.x * 256 + threadIdx.x;
    int stride = gridDim.x * 256;
    for (int e = i; e < N_EDGES / 4; e += stride) {
        int4 d = d4[e];
        atomicAdd(&cnt[d.x], 1);
        atomicAdd(&cnt[d.y], 1);
        atomicAdd(&cnt[d.z], 1);
        atomicAdd(&cnt[d.w], 1);
    }
}

// ---- CSR build: exclusive scan over PADDED counts (ceil(cnt/4)*4) ----
__global__ __launch_bounds__(SCAN_BLK) void k_scan1(const int* __restrict__ cnt,
                                                    int* __restrict__ rp,
                                                    int* __restrict__ bsum)
{
    __shared__ int s[SCAN_BLK];
    int tid = threadIdx.x;
    int base = blockIdx.x * SCAN_EPB + tid * 4;
    int v0 = (base + 0 < N_NODES) ? ((cnt[base + 0] + 3) & ~3) : 0;
    int v1 = (base + 1 < N_NODES) ? ((cnt[base + 1] + 3) & ~3) : 0;
    int v2 = (base + 2 < N_NODES) ? ((cnt[base + 2] + 3) & ~3) : 0;
    int v3 = (base + 3 < N_NODES) ? ((cnt[base + 3] + 3) & ~3) : 0;
    int tsum = v0 + v1 + v2 + v3;
    s[tid] = tsum;
    __syncthreads();
    for (int off = 1; off < SCAN_BLK; off <<= 1) {
        int t = (tid >= off) ? s[tid - off] : 0;
        __syncthreads();
        s[tid] += t;
        __syncthreads();
    }
    int excl = s[tid] - tsum;
    if (base + 0 < N_NODES) rp[base + 0] = excl;
    if (base + 1 < N_NODES) rp[base + 1] = excl + v0;
    if (base + 2 < N_NODES) rp[base + 2] = excl + v0 + v1;
    if (base + 3 < N_NODES) rp[base + 3] = excl + v0 + v1 + v2;
    if (tid == SCAN_BLK - 1) bsum[blockIdx.x] = s[tid];
}

__global__ void k_scan2(int* __restrict__ bsum, int* __restrict__ rp)
{
    if (threadIdx.x == 0 && blockIdx.x == 0) {
        int acc = 0;
        for (int b = 0; b < SCAN_NB; ++b) { int t = bsum[b]; bsum[b] = acc; acc += t; }
        rp[N_NODES] = acc;   // total padded edge slots
    }
}

__global__ __launch_bounds__(SCAN_BLK) void k_scan3(int* __restrict__ rp,
                                                    const int* __restrict__ bsum,
                                                    int* __restrict__ cursor)
{
    int tid = threadIdx.x, blk = blockIdx.x;
    int add = bsum[blk];
    int base = blk * SCAN_EPB + tid * 4;
    #pragma unroll
    for (int i = 0; i < 4; ++i) {
        int idx = base + i;
        if (idx < N_NODES) { int v = rp[idx] + add; rp[idx] = v; cursor[idx] = v; }
    }
}

// ---- CSR build: zero-fill pad slots (mult=0); plain stores so L2 merges lines ----
__global__ __launch_bounds__(256) void k_padfill(const int* __restrict__ rp,
                                                 const int* __restrict__ cnt,
                                                 i4* __restrict__ erec)
{
    int n = blockIdx.x * 256 + threadIdx.x;
    if (n >= N_NODES) return;
    int s = rp[n] + cnt[n], e = rp[n + 1];
    i4 z = (i4){0, 0, 0, 0};
    for (int p = s; p < e; ++p) erec[p] = z;
}

// -- CSR build: scatter 16B records {src*16, bf16x2, bf16x2, mult=1.0f}, 4 edges/thread --
// Plain stores: dst-sorted slots are adjacent, L2 write-merges partial lines.
__global__ __launch_bounds__(256) void k_scatter(const int* __restrict__ ei,
                                                 const float* __restrict__ ea,
                                                 int* __restrict__ cursor,
                                                 i4* __restrict__ erec)
{
    const int4* s4 = reinterpret_cast<const int4*>(ei);
    const int4* d4 = reinterpret_cast<const int4*>(ei + N_EDGES);
    const float4* a4 = reinterpret_cast<const float4*>(ea);
    const int one = 0x3f800000;   // 1.0f bits
    int i = blockIdx.x * 256 + threadIdx.x;
    int stride = gridDim.x * 256;
    for (int e = i; e < N_EDGES / 4; e += stride) {
        int4 s = s4[e];
        int4 d = d4[e];
        float4 a0 = a4[e * 4 + 0], a1 = a4[e * 4 + 1];
        float4 a2 = a4[e * 4 + 2], a3 = a4[e * 4 + 3];
        int p0 = atomicAdd(&cursor[d.x], 1);
        int p1 = atomicAdd(&cursor[d.y], 1);
        int p2 = atomicAdd(&cursor[d.z], 1);
        int p3 = atomicAdd(&cursor[d.w], 1);
        erec[p0] = (i4){ s.x * 16,
            (int)((unsigned)f2bf(a0.x) | ((unsigned)f2bf(a0.y) << 16)),
            (int)((unsigned)f2bf(a0.z) | ((unsigned)f2bf(a0.w) << 16)), one };
        erec[p1] = (i4){ s.y * 16,
            (int)((unsigned)f2bf(a1.x) | ((unsigned)f2bf(a1.y) << 16)),
            (int)((unsigned)f2bf(a1.z) | ((unsigned)f2bf(a1.w) << 16)), one };
        erec[p2] = (i4){ s.z * 16,
            (int)((unsigned)f2bf(a2.x) | ((unsigned)f2bf(a2.y) << 16)),
            (int)((unsigned)f2bf(a2.z) | ((unsigned)f2bf(a2.w) << 16)), one };
        erec[p3] = (i4){ s.w * 16,
            (int)((unsigned)f2bf(a3.x) | ((unsigned)f2bf(a3.y) << 16)),
            (int)((unsigned)f2bf(a3.z) | ((unsigned)f2bf(a3.w) << 16)), one };
    }
}

// -------- graph rowptr from sorted batch (boundary detect, no atomics) --------
__global__ __launch_bounds__(256) void k_gptr(const int* __restrict__ batch,
                                              int* __restrict__ gp)
{
    int n = blockIdx.x * 256 + threadIdx.x;
    if (n >= N_NODES) return;
    int b  = batch[n];
    int bp = (n == 0) ? -1 : batch[n - 1];
    for (int g = bp + 1; g <= b; ++g) gp[g] = n;
    if (n == N_NODES - 1)
        for (int g = b + 1; g <= N_GRAPHS; ++g) gp[g] = N_NODES;
}

// ---------------- input projection: h = relu(x @ W_in + b_in) -> bf16 ----------------
__global__ __launch_bounds__(256) void k_input_proj(
        const float* __restrict__ x, const float* __restrict__ Win,
        const float* __restrict__ bin, u16* __restrict__ h)
{
    __shared__ float Ws[F_IN * H];
    __shared__ float bs[H];
    int tid = threadIdx.x;
    for (int i = tid; i < F_IN * H; i += 256) Ws[i] = Win[i];
    if (tid < H) bs[tid] = bin[tid];
    __syncthreads();
    int lane = tid & 63;
    int wid  = tid >> 6;
    for (int n = blockIdx.x * 4 + wid; n < N_NODES; n += gridDim.x * 4) {
        const float* xr = x + (size_t)n * F_IN;
        float acc = bs[lane];
        #pragma unroll
        for (int k = 0; k < F_IN; ++k)
            acc = fmaf(xr[k], Ws[k * H + lane], acc);
        h[(size_t)n * H + lane] = f2bf(fmaxf(acc, 0.f));
    }
}

// ---- fused layer: z = h + sum_in relu(h[src]+e@We+be); h' = relu(mlp(z)) ----
// Phase 1: 16-lane groups, branch-free 4-edge unrolled body (padded lists), no prefetch.
// Phase 2: tiled 64x64 MLP on LDS z tile.
__global__ __launch_bounds__(256, 8) void k_layer(
        const int* __restrict__ rp, const i4* __restrict__ erec,
        const float* __restrict__ We_l, const float* __restrict__ be_l,
        const float* __restrict__ W1l, const float* __restrict__ b1l,
        const float* __restrict__ W2l, const float* __restrict__ b2l,
        const u16* __restrict__ hin, u16* __restrict__ hout)
{
    __shared__ float zs[64][65];
    int tid  = threadIdx.x;
    int lane = tid & 63, w = tid >> 6;
    int q = lane >> 4, r = lane & 15;     // group q in [0,4), lane-in-group r
    int n0 = blockIdx.x * 64;
    const ushort4* hin4 = reinterpret_cast<const ushort4*>(hin);

    // per-lane: We columns 4r..4r+3 (4 attr rows) + bias
    float4 wr0 = *reinterpret_cast<const float4*>(We_l + 0 * H + r * 4);
    float4 wr1 = *reinterpret_cast<const float4*>(We_l + 1 * H + r * 4);
    float4 wr2 = *reinterpret_cast<const float4*>(We_l + 2 * H + r * 4);
    float4 wr3 = *reinterpret_cast<const float4*>(We_l + 3 * H + r * 4);
    float4 bv  = *reinterpret_cast<const float4*>(be_l + r * 4);

    for (int t = 0; t < 4; ++t) {
        int row = w * 16 + t * 4 + q;
        int n   = n0 + row;
        float4 acc = make_float4(0.f, 0.f, 0.f, 0.f);
        if (n < N_NODES) {
            ushort4 hs = hin4[(unsigned)n * 16 + r];     // self term (eps=0)
            acc.x = bf2f(hs.x); acc.y = bf2f(hs.y);
            acc.z = bf2f(hs.z); acc.w = bf2f(hs.w);
            int j0 = rp[n], j1 = rp[n + 1];              // padded to multiple of 4
            for (int j = j0; j < j1; j += 4) {
                i4 R[4];
                ushort4 G[4];
                #pragma unroll
                for (int k = 0; k < 4; ++k)
                    R[k] = __builtin_nontemporal_load(&erec[j + k]);
                #pragma unroll
                for (int k = 0; k < 4; ++k)
                    G[k] = hin4[(unsigned)R[k].x + r];   // R.x = src*16
                #pragma unroll
                for (int k = 0; k < 4; ++k) {
                    float mult = __int_as_float(R[k].w);
                    float ax = bf2f((u16)(R[k].y & 0xffff));
                    float ay = bf2f((u16)(((unsigned)R[k].y) >> 16));
                    float az = bf2f((u16)(R[k].z & 0xffff));
                    float aw = bf2f((u16)(((unsigned)R[k].z) >> 16));
                    float e0 = fmaf(ax, wr0.x, fmaf(ay, wr1.x, fmaf(az, wr2.x, fmaf(aw, wr3.x, bv.x))));
                    float e1 = fmaf(ax, wr0.y, fmaf(ay, wr1.y, fmaf(az, wr2.y, fmaf(aw, wr3.y, bv.y))));
                    float e2 = fmaf(ax, wr0.z, fmaf(ay, wr1.z, fmaf(az, wr2.z, fmaf(aw, wr3.z, bv.z))));
                    float e3 = fmaf(ax, wr0.w, fmaf(ay, wr1.w, fmaf(az, wr2.w, fmaf(aw, wr3.w, bv.w))));
                    acc.x = fmaf(mult, fmaxf(bf2f(G[k].x) + e0, 0.f), acc.x);
                    acc.y = fmaf(mult, fmaxf(bf2f(G[k].y) + e1, 0.f), acc.y);
                    acc.z = fmaf(mult, fmaxf(bf2f(G[k].z) + e2, 0.f), acc.z);
                    acc.w = fmaf(mult, fmaxf(bf2f(G[k].w) + e3, 0.f), acc.w);
                }
            }
        }
        zs[row][r * 4 + 0] = acc.x;
        zs[row][r * 4 + 1] = acc.y;
        zs[row][r * 4 + 2] = acc.z;
        zs[row][r * 4 + 3] = acc.w;
    }
    __syncthreads();

    // phase 2: MLP on the 64x64 tile
    int tr = (tid >> 4) * 4, tc = (tid & 15) * 4;
    float a1[4][4];
    #pragma unroll
    for (int i = 0; i < 4; ++i)
        #pragma unroll
        for (int j = 0; j < 4; ++j) a1[i][j] = b1l[tc + j];
    #pragma unroll 8
    for (int k = 0; k < H; ++k) {
        float4 wv = *reinterpret_cast<const float4*>(&W1l[k * H + tc]);
        #pragma unroll
        for (int i = 0; i < 4; ++i) {
            float zr = zs[tr + i][k];
            a1[i][0] = fmaf(zr, wv.x, a1[i][0]);
            a1[i][1] = fmaf(zr, wv.y, a1[i][1]);
            a1[i][2] = fmaf(zr, wv.z, a1[i][2]);
            a1[i][3] = fmaf(zr, wv.w, a1[i][3]);
        }
    }
    __syncthreads();
    #pragma unroll
    for (int i = 0; i < 4; ++i)
        #pragma unroll
        for (int j = 0; j < 4; ++j) zs[tr + i][tc + j] = fmaxf(a1[i][j], 0.f);
    __syncthreads();

    float a2[4][4];
    #pragma unroll
    for (int i = 0; i < 4; ++i)
        #pragma unroll
        for (int j = 0; j < 4; ++j) a2[i][j] = b2l[tc + j];
    #pragma unroll 8
    for (int k = 0; k < H; ++k) {
        float4 wv = *reinterpret_cast<const float4*>(&W2l[k * H + tc]);
        #pragma unroll
        for (int i = 0; i < 4; ++i) {
            float zr = zs[tr + i][k];
            a2[i][0] = fmaf(zr, wv.x, a2[i][0]);
            a2[i][1] = fmaf(zr, wv.y, a2[i][1]);
            a2[i][2] = fmaf(zr, wv.z, a2[i][2]);
            a2[i][3] = fmaf(zr, wv.w, a2[i][3]);
        }
    }
    #pragma unroll
    for (int i = 0; i < 4; ++i) {
        int n = n0 + tr + i;
        if (n < N_NODES) {
            ushort4 o;
            o.x = f2bf(fmaxf(a2[i][0], 0.f));
            o.y = f2bf(fmaxf(a2[i][1], 0.f));
            o.z = f2bf(fmaxf(a2[i][2], 0.f));
            o.w = f2bf(fmaxf(a2[i][3], 0.f));
            *reinterpret_cast<ushort4*>(&hout[(size_t)n * H + tc]) = o;
        }
    }
}

// ------- fused pool + LN + head: one wave per graph, 4-deep accumulation -------
__global__ __launch_bounds__(64) void k_poolfinal(
        const u16* __restrict__ hb, const int* __restrict__ gp,
        const float* __restrict__ Wout, const float* __restrict__ bout,
        float* __restrict__ out)
{
    int g = blockIdx.x, lane = threadIdx.x;
    int a = gp[g], b = gp[g + 1];
    float s0 = 0.f, s1 = 0.f, s2a = 0.f, s3 = 0.f;
    int n = a;
    for (; n + 3 < b; n += 4) {
        s0  += bf2f(hb[(size_t)n * H + lane]);
        s1  += bf2f(hb[(size_t)(n + 1) * H + lane]);
        s2a += bf2f(hb[(size_t)(n + 2) * H + lane]);
        s3  += bf2f(hb[(size_t)(n + 3) * H + lane]);
    }
    for (; n < b; ++n) s0 += bf2f(hb[(size_t)n * H + lane]);
    float v = ((s0 + s1) + (s2a + s3)) / fmaxf((float)(b - a), 1.f);
    float t = v;
    #pragma unroll
    for (int off = 32; off; off >>= 1) t += __shfl_xor(t, off);
    float mu = t * (1.0f / H);
    float d  = v - mu;
    float s2 = d * d;
    #pragma unroll
    for (int off = 32; off; off >>= 1) s2 += __shfl_xor(s2, off);
    float var = s2 * (1.0f / H);
    float y = d * rsqrtf(var + LN_EPS);
    float p = y * Wout[lane];
    #pragma unroll
    for (int off = 32; off; off >>= 1) p += __shfl_xor(p, off);
    if (lane == 0) out[g] = p + bout[0];
}

extern "C" void kernel_launch(void* const* d_in, const int* in_sizes, int n_in,
                              void* d_out, int out_size, void* d_ws, size_t ws_size,
                              hipStream_t stream)
{
    const float* x     = (const float*)d_in[0];
    const int*   ei    = (const int*)  d_in[1];
    const float* ea    = (const float*)d_in[2];
    const int*   batch = (const int*)  d_in[3];
    const float* Win   = (const float*)d_in[4];
    const float* bin   = (const float*)d_in[5];
    const float* We    = (const float*)d_in[6];
    const float* be    = (const float*)d_in[7];
    const float* W1    = (const float*)d_in[8];
    const float* b1    = (const float*)d_in[9];
    const float* W2    = (const float*)d_in[10];
    const float* b2    = (const float*)d_in[11];
    const float* Wout  = (const float*)d_in[12];
    const float* bout  = (const float*)d_in[13];
    float* out = (float*)d_out;

    char* ws = (char*)d_ws;
    size_t off = 0;
    auto alloc = [&](size_t bytes) -> char* {
        char* p = ws + off;
        off += (bytes + 255) & ~(size_t)255;
        return p;
    };
    const size_t HBH   = (size_t)N_NODES * H * sizeof(u16);              // 12.8 MB
    const size_t NEPAD = (size_t)N_EDGES + 3 * (size_t)N_NODES + 64;     // padded capacity + tail slack
    u16*  h0     = (u16*) alloc(HBH);
    u16*  h1     = (u16*) alloc(HBH);
    i4*   erec   = (i4*)  alloc(NEPAD * sizeof(i4));                     // ~30.4 MB
    int*  cnt    = (int*) alloc((size_t)N_NODES * sizeof(int));
    int*  rp     = (int*) alloc((size_t)(N_NODES + 1) * sizeof(int));
    int*  cursor = (int*) alloc((size_t)N_NODES * sizeof(int));
    int*  bsum   = (int*) alloc((size_t)SCAN_NB * sizeof(int));
    int*  gp     = (int*) alloc((size_t)(N_GRAPHS + 1) * sizeof(int));

    // ---- CSR build (dst-sorted padded edge records, attrs bf16, src pre-scaled) ----
    (void)hipMemsetAsync(cnt, 0, (size_t)N_NODES * sizeof(int), stream);
    k_hist<<<1600, 256, 0, stream>>>(ei, cnt);
    k_scan1<<<SCAN_NB, SCAN_BLK, 0, stream>>>(cnt, rp, bsum);
    k_scan2<<<1, 64, 0, stream>>>(bsum, rp);
    k_scan3<<<SCAN_NB, SCAN_BLK, 0, stream>>>(rp, bsum, cursor);
    k_padfill<<<(N_NODES + 255) / 256, 256, 0, stream>>>(rp, cnt, erec);
    k_scatter<<<1600, 256, 0, stream>>>(ei, ea, cursor, erec);
    k_gptr<<<(N_NODES + 255) / 256, 256, 0, stream>>>(batch, gp);

    // ---- network ----
    k_input_proj<<<1024, 256, 0, stream>>>(x, Win, bin, h0);
    u16* cur = h0;
    u16* nxt = h1;
    const int NBLK = (N_NODES + 63) / 64;
    for (int l = 0; l < N_LAYERS; ++l) {
        k_layer<<<NBLK, 256, 0, stream>>>(rp, erec,
                We + (size_t)l * 4 * H, be + (size_t)l * H,
                W1 + (size_t)l * H * H, b1 + (size_t)l * H,
                W2 + (size_t)l * H * H, b2 + (size_t)l * H,
                cur, nxt);
        u16* t = cur; cur = nxt; nxt = t;
    }

    k_poolfinal<<<N_GRAPHS, 64, 0, stream>>>(cur, gp, Wout, bout, out);
}

// Round 10
// 759.972 us; speedup vs baseline: 1.2148x; 1.0081x over previous
//
#include <hip/hip_runtime.h>

#define N_NODES  100000
#define N_EDGES  1600000
#define N_GRAPHS 2000
#define F_IN     32
#define H        64
#define N_LAYERS 5
#define LN_EPS   1e-5f

#define SCAN_BLK 512
#define SCAN_EPB 2048                                  // 4 elems/thread
#define SCAN_NB  ((N_NODES + SCAN_EPB - 1) / SCAN_EPB) // 49 blocks

typedef unsigned short u16;
typedef int i4 __attribute__((ext_vector_type(4)));    // clang vector type

__device__ __forceinline__ float bf2f(u16 v) {
    union { unsigned u; float f; } c; c.u = ((unsigned)v) << 16; return c.f;
}
__device__ __forceinline__ u16 f2bf(float f) {   // round-to-nearest-even
    union { float f; unsigned u; } c; c.f = f;
    return (u16)((c.u + 0x7fffu + ((c.u >> 16) & 1u)) >> 16);
}

// ---------------- CSR build: histogram of dst (int4-vectorized) ----------------
__global__ __launch_bounds__(256) void k_hist(const int* __restrict__ ei,
                                              int* __restrict__ cnt)
{
    const int4* d4 = reinterpret_cast<const int4*>(ei + N_EDGES);
    int i = blockIdx.x * 256 + threadIdx.x;
    int stride = gridDim.x * 256;
    for (int e = i; e < N_EDGES / 4; e += stride) {
        int4 d = d4[e];
        atomicAdd(&cnt[d.x], 1);
        atomicAdd(&cnt[d.y], 1);
        atomicAdd(&cnt[d.z], 1);
        atomicAdd(&cnt[d.w], 1);
    }
}

// ---- CSR build: exclusive scan over PADDED counts (ceil(cnt/4)*4) ----
__global__ __launch_bounds__(SCAN_BLK) void k_scan1(const int* __restrict__ cnt,
                                                    int* __restrict__ rp,
                                                    int* __restrict__ bsum)
{
    __shared__ int s[SCAN_BLK];
    int tid = threadIdx.x;
    int base = blockIdx.x * SCAN_EPB + tid * 4;
    int v0 = (base + 0 < N_NODES) ? ((cnt[base + 0] + 3) & ~3) : 0;
    int v1 = (base + 1 < N_NODES) ? ((cnt[base + 1] + 3) & ~3) : 0;
    int v2 = (base + 2 < N_NODES) ? ((cnt[base + 2] + 3) & ~3) : 0;
    int v3 = (base + 3 < N_NODES) ? ((cnt[base + 3] + 3) & ~3) : 0;
    int tsum = v0 + v1 + v2 + v3;
    s[tid] = tsum;
    __syncthreads();
    for (int off = 1; off < SCAN_BLK; off <<= 1) {
        int t = (tid >= off) ? s[tid - off] : 0;
        __syncthreads();
        s[tid] += t;
        __syncthreads();
    }
    int excl = s[tid] - tsum;
    if (base + 0 < N_NODES) rp[base + 0] = excl;
    if (base + 1 < N_NODES) rp[base + 1] = excl + v0;
    if (base + 2 < N_NODES) rp[base + 2] = excl + v0 + v1;
    if (base + 3 < N_NODES) rp[base + 3] = excl + v0 + v1 + v2;
    if (tid == SCAN_BLK - 1) bsum[blockIdx.x] = s[tid];
}

__global__ void k_scan2(int* __restrict__ bsum, int* __restrict__ rp)
{
    if (threadIdx.x == 0 && blockIdx.x == 0) {
        int acc = 0;
        for (int b = 0; b < SCAN_NB; ++b) { int t = bsum[b]; bsum[b] = acc; acc += t; }
        rp[N_NODES] = acc;   // total padded edge slots
    }
}

__global__ __launch_bounds__(SCAN_BLK) void k_scan3(int* __restrict__ rp,
                                                    const int* __restrict__ bsum,
                                                    int* __restrict__ cursor)
{
    int tid = threadIdx.x, blk = blockIdx.x;
    int add = bsum[blk];
    int base = blk * SCAN_EPB + tid * 4;
    #pragma unroll
    for (int i = 0; i < 4; ++i) {
        int idx = base + i;
        if (idx < N_NODES) { int v = rp[idx] + add; rp[idx] = v; cursor[idx] = v; }
    }
}

// ---- CSR build: zero-fill pad slots (mult=0) ----
__global__ __launch_bounds__(256) void k_padfill(const int* __restrict__ rp,
                                                 const int* __restrict__ cnt,
                                                 i4* __restrict__ erec)
{
    int n = blockIdx.x * 256 + threadIdx.x;
    if (n >= N_NODES) return;
    int s = rp[n] + cnt[n], e = rp[n + 1];
    i4 z = (i4){0, 0, 0, 0};
    for (int p = s; p < e; ++p) erec[p] = z;
}

// -- CSR build: scatter 16B records {src*16, bf16x2, bf16x2, mult=1.0f} --
// One edge per thread, large grid: maximize outstanding atomic/store chains.
__global__ __launch_bounds__(256) void k_scatter(const int* __restrict__ ei,
                                                 const float* __restrict__ ea,
                                                 int* __restrict__ cursor,
                                                 i4* __restrict__ erec)
{
    const float4* a4 = reinterpret_cast<const float4*>(ea);
    const int one = 0x3f800000;   // 1.0f bits
    int i = blockIdx.x * 256 + threadIdx.x;
    int stride = gridDim.x * 256;
    for (int e = i; e < N_EDGES; e += stride) {
        int s = ei[e];
        int d = ei[N_EDGES + e];
        float4 a = a4[e];
        int pos = atomicAdd(&cursor[d], 1);
        erec[pos] = (i4){ s * 16,
            (int)((unsigned)f2bf(a.x) | ((unsigned)f2bf(a.y) << 16)),
            (int)((unsigned)f2bf(a.z) | ((unsigned)f2bf(a.w) << 16)), one };
    }
}

// -------- graph rowptr from sorted batch (boundary detect, no atomics) --------
__global__ __launch_bounds__(256) void k_gptr(const int* __restrict__ batch,
                                              int* __restrict__ gp)
{
    int n = blockIdx.x * 256 + threadIdx.x;
    if (n >= N_NODES) return;
    int b  = batch[n];
    int bp = (n == 0) ? -1 : batch[n - 1];
    for (int g = bp + 1; g <= b; ++g) gp[g] = n;
    if (n == N_NODES - 1)
        for (int g = b + 1; g <= N_GRAPHS; ++g) gp[g] = N_NODES;
}

// ---------------- input projection: h = relu(x @ W_in + b_in) -> bf16 ----------------
__global__ __launch_bounds__(256) void k_input_proj(
        const float* __restrict__ x, const float* __restrict__ Win,
        const float* __restrict__ bin, u16* __restrict__ h)
{
    __shared__ float Ws[F_IN * H];
    __shared__ float bs[H];
    int tid = threadIdx.x;
    for (int i = tid; i < F_IN * H; i += 256) Ws[i] = Win[i];
    if (tid < H) bs[tid] = bin[tid];
    __syncthreads();
    int lane = tid & 63;
    int wid  = tid >> 6;
    for (int n = blockIdx.x * 4 + wid; n < N_NODES; n += gridDim.x * 4) {
        const float* xr = x + (size_t)n * F_IN;
        float acc = bs[lane];
        #pragma unroll
        for (int k = 0; k < F_IN; ++k)
            acc = fmaf(xr[k], Ws[k * H + lane], acc);
        h[(size_t)n * H + lane] = f2bf(fmaxf(acc, 0.f));
    }
}

// ---- fused layer: z = h + sum_in relu(h[src]+e@We+be); h' = relu(mlp(z)) ----
// Phase 1: 16-lane groups, branch-free 4-edge unrolled body (padded lists).
// Phase 2: tiled 64x64 MLP on LDS z tile.  (r9 body, frozen)
__global__ __launch_bounds__(256, 8) void k_layer(
        const int* __restrict__ rp, const i4* __restrict__ erec,
        const float* __restrict__ We_l, const float* __restrict__ be_l,
        const float* __restrict__ W1l, const float* __restrict__ b1l,
        const float* __restrict__ W2l, const float* __restrict__ b2l,
        const u16* __restrict__ hin, u16* __restrict__ hout)
{
    __shared__ float zs[64][65];
    int tid  = threadIdx.x;
    int lane = tid & 63, w = tid >> 6;
    int q = lane >> 4, r = lane & 15;     // group q in [0,4), lane-in-group r
    int n0 = blockIdx.x * 64;
    const ushort4* hin4 = reinterpret_cast<const ushort4*>(hin);

    // per-lane: We columns 4r..4r+3 (4 attr rows) + bias
    float4 wr0 = *reinterpret_cast<const float4*>(We_l + 0 * H + r * 4);
    float4 wr1 = *reinterpret_cast<const float4*>(We_l + 1 * H + r * 4);
    float4 wr2 = *reinterpret_cast<const float4*>(We_l + 2 * H + r * 4);
    float4 wr3 = *reinterpret_cast<const float4*>(We_l + 3 * H + r * 4);
    float4 bv  = *reinterpret_cast<const float4*>(be_l + r * 4);

    for (int t = 0; t < 4; ++t) {
        int row = w * 16 + t * 4 + q;
        int n   = n0 + row;
        float4 acc = make_float4(0.f, 0.f, 0.f, 0.f);
        if (n < N_NODES) {
            ushort4 hs = hin4[(unsigned)n * 16 + r];     // self term (eps=0)
            acc.x = bf2f(hs.x); acc.y = bf2f(hs.y);
            acc.z = bf2f(hs.z); acc.w = bf2f(hs.w);
            int j0 = rp[n], j1 = rp[n + 1];              // padded to multiple of 4
            for (int j = j0; j < j1; j += 4) {
                i4 R[4];
                ushort4 G[4];
                #pragma unroll
                for (int k = 0; k < 4; ++k)
                    R[k] = __builtin_nontemporal_load(&erec[j + k]);
                #pragma unroll
                for (int k = 0; k < 4; ++k)
                    G[k] = hin4[(unsigned)R[k].x + r];   // R.x = src*16
                #pragma unroll
                for (int k = 0; k < 4; ++k) {
                    float mult = __int_as_float(R[k].w);
                    float ax = bf2f((u16)(R[k].y & 0xffff));
                    float ay = bf2f((u16)(((unsigned)R[k].y) >> 16));
                    float az = bf2f((u16)(R[k].z & 0xffff));
                    float aw = bf2f((u16)(((unsigned)R[k].z) >> 16));
                    float e0 = fmaf(ax, wr0.x, fmaf(ay, wr1.x, fmaf(az, wr2.x, fmaf(aw, wr3.x, bv.x))));
                    float e1 = fmaf(ax, wr0.y, fmaf(ay, wr1.y, fmaf(az, wr2.y, fmaf(aw, wr3.y, bv.y))));
                    float e2 = fmaf(ax, wr0.z, fmaf(ay, wr1.z, fmaf(az, wr2.z, fmaf(aw, wr3.z, bv.z))));
                    float e3 = fmaf(ax, wr0.w, fmaf(ay, wr1.w, fmaf(az, wr2.w, fmaf(aw, wr3.w, bv.w))));
                    acc.x = fmaf(mult, fmaxf(bf2f(G[k].x) + e0, 0.f), acc.x);
                    acc.y = fmaf(mult, fmaxf(bf2f(G[k].y) + e1, 0.f), acc.y);
                    acc.z = fmaf(mult, fmaxf(bf2f(G[k].z) + e2, 0.f), acc.z);
                    acc.w = fmaf(mult, fmaxf(bf2f(G[k].w) + e3, 0.f), acc.w);
                }
            }
        }
        zs[row][r * 4 + 0] = acc.x;
        zs[row][r * 4 + 1] = acc.y;
        zs[row][r * 4 + 2] = acc.z;
        zs[row][r * 4 + 3] = acc.w;
    }
    __syncthreads();

    // phase 2: MLP on the 64x64 tile
    int tr = (tid >> 4) * 4, tc = (tid & 15) * 4;
    float a1[4][4];
    #pragma unroll
    for (int i = 0; i < 4; ++i)
        #pragma unroll
        for (int j = 0; j < 4; ++j) a1[i][j] = b1l[tc + j];
    #pragma unroll 8
    for (int k = 0; k < H; ++k) {
        float4 wv = *reinterpret_cast<const float4*>(&W1l[k * H + tc]);
        #pragma unroll
        for (int i = 0; i < 4; ++i) {
            float zr = zs[tr + i][k];
            a1[i][0] = fmaf(zr, wv.x, a1[i][0]);
            a1[i][1] = fmaf(zr, wv.y, a1[i][1]);
            a1[i][2] = fmaf(zr, wv.z, a1[i][2]);
            a1[i][3] = fmaf(zr, wv.w, a1[i][3]);
        }
    }
    __syncthreads();
    #pragma unroll
    for (int i = 0; i < 4; ++i)
        #pragma unroll
        for (int j = 0; j < 4; ++j) zs[tr + i][tc + j] = fmaxf(a1[i][j], 0.f);
    __syncthreads();

    float a2[4][4];
    #pragma unroll
    for (int i = 0; i < 4; ++i)
        #pragma unroll
        for (int j = 0; j < 4; ++j) a2[i][j] = b2l[tc + j];
    #pragma unroll 8
    for (int k = 0; k < H; ++k) {
        float4 wv = *reinterpret_cast<const float4*>(&W2l[k * H + tc]);
        #pragma unroll
        for (int i = 0; i < 4; ++i) {
            float zr = zs[tr + i][k];
            a2[i][0] = fmaf(zr, wv.x, a2[i][0]);
            a2[i][1] = fmaf(zr, wv.y, a2[i][1]);
            a2[i][2] = fmaf(zr, wv.z, a2[i][2]);
            a2[i][3] = fmaf(zr, wv.w, a2[i][3]);
        }
    }
    #pragma unroll
    for (int i = 0; i < 4; ++i) {
        int n = n0 + tr + i;
        if (n < N_NODES) {
            ushort4 o;
            o.x = f2bf(fmaxf(a2[i][0], 0.f));
            o.y = f2bf(fmaxf(a2[i][1], 0.f));
            o.z = f2bf(fmaxf(a2[i][2], 0.f));
            o.w = f2bf(fmaxf(a2[i][3], 0.f));
            *reinterpret_cast<ushort4*>(&hout[(size_t)n * H + tc]) = o;
        }
    }
}

// ------- fused pool + LN + head: one wave per graph, 4-deep accumulation -------
__global__ __launch_bounds__(64) void k_poolfinal(
        const u16* __restrict__ hb, const int* __restrict__ gp,
        const float* __restrict__ Wout, const float* __restrict__ bout,
        float* __restrict__ out)
{
    int g = blockIdx.x, lane = threadIdx.x;
    int a = gp[g], b = gp[g + 1];
    float s0 = 0.f, s1 = 0.f, s2a = 0.f, s3 = 0.f;
    int n = a;
    for (; n + 3 < b; n += 4) {
        s0  += bf2f(hb[(size_t)n * H + lane]);
        s1  += bf2f(hb[(size_t)(n + 1) * H + lane]);
        s2a += bf2f(hb[(size_t)(n + 2) * H + lane]);
        s3  += bf2f(hb[(size_t)(n + 3) * H + lane]);
    }
    for (; n < b; ++n) s0 += bf2f(hb[(size_t)n * H + lane]);
    float v = ((s0 + s1) + (s2a + s3)) / fmaxf((float)(b - a), 1.f);
    float t = v;
    #pragma unroll
    for (int off = 32; off; off >>= 1) t += __shfl_xor(t, off);
    float mu = t * (1.0f / H);
    float d  = v - mu;
    float s2 = d * d;
    #pragma unroll
    for (int off = 32; off; off >>= 1) s2 += __shfl_xor(s2, off);
    float var = s2 * (1.0f / H);
    float y = d * rsqrtf(var + LN_EPS);
    float p = y * Wout[lane];
    #pragma unroll
    for (int off = 32; off; off >>= 1) p += __shfl_xor(p, off);
    if (lane == 0) out[g] = p + bout[0];
}

extern "C" void kernel_launch(void* const* d_in, const int* in_sizes, int n_in,
                              void* d_out, int out_size, void* d_ws, size_t ws_size,
                              hipStream_t stream)
{
    const float* x     = (const float*)d_in[0];
    const int*   ei    = (const int*)  d_in[1];
    const float* ea    = (const float*)d_in[2];
    const int*   batch = (const int*)  d_in[3];
    const float* Win   = (const float*)d_in[4];
    const float* bin   = (const float*)d_in[5];
    const float* We    = (const float*)d_in[6];
    const float* be    = (const float*)d_in[7];
    const float* W1    = (const float*)d_in[8];
    const float* b1    = (const float*)d_in[9];
    const float* W2    = (const float*)d_in[10];
    const float* b2    = (const float*)d_in[11];
    const float* Wout  = (const float*)d_in[12];
    const float* bout  = (const float*)d_in[13];
    float* out = (float*)d_out;

    char* ws = (char*)d_ws;
    size_t off = 0;
    auto alloc = [&](size_t bytes) -> char* {
        char* p = ws + off;
        off += (bytes + 255) & ~(size_t)255;
        return p;
    };
    const size_t HBH   = (size_t)N_NODES * H * sizeof(u16);              // 12.8 MB
    const size_t NEPAD = (size_t)N_EDGES + 3 * (size_t)N_NODES + 64;     // padded capacity + tail slack
    u16*  h0     = (u16*) alloc(HBH);
    u16*  h1     = (u16*) alloc(HBH);
    i4*   erec   = (i4*)  alloc(NEPAD * sizeof(i4));                     // ~30.4 MB
    int*  cnt    = (int*) alloc((size_t)N_NODES * sizeof(int));
    int*  rp     = (int*) alloc((size_t)(N_NODES + 1) * sizeof(int));
    int*  cursor = (int*) alloc((size_t)N_NODES * sizeof(int));
    int*  bsum   = (int*) alloc((size_t)SCAN_NB * sizeof(int));
    int*  gp     = (int*) alloc((size_t)(N_GRAPHS + 1) * sizeof(int));

    // ---- CSR build (dst-sorted padded edge records, attrs bf16, src pre-scaled) ----
    (void)hipMemsetAsync(cnt, 0, (size_t)N_NODES * sizeof(int), stream);
    k_hist<<<2048, 256, 0, stream>>>(ei, cnt);
    k_scan1<<<SCAN_NB, SCAN_BLK, 0, stream>>>(cnt, rp, bsum);
    k_scan2<<<1, 64, 0, stream>>>(bsum, rp);
    k_scan3<<<SCAN_NB, SCAN_BLK, 0, stream>>>(rp, bsum, cursor);
    k_padfill<<<(N_NODES + 255) / 256, 256, 0, stream>>>(rp, cnt, erec);
    k_scatter<<<4096, 256, 0, stream>>>(ei, ea, cursor, erec);
    k_gptr<<<(N_NODES + 255) / 256, 256, 0, stream>>>(batch, gp);

    // ---- network ----
    k_input_proj<<<1024, 256, 0, stream>>>(x, Win, bin, h0);
    u16* cur = h0;
    u16* nxt = h1;
    const int NBLK = (N_NODES + 63) / 64;
    for (int l = 0; l < N_LAYERS; ++l) {
        k_layer<<<NBLK, 256, 0, stream>>>(rp, erec,
                We + (size_t)l * 4 * H, be + (size_t)l * H,
                W1 + (size_t)l * H * H, b1 + (size_t)l * H,
                W2 + (size_t)l * H * H, b2 + (size_t)l * H,
                cur, nxt);
        u16* t = cur; cur = nxt; nxt = t;
    }

    k_poolfinal<<<N_GRAPHS, 64, 0, stream>>>(cur, gp, Wout, bout, out);
}

// Round 11
// 702.686 us; speedup vs baseline: 1.3138x; 1.0815x over previous
//
#include <hip/hip_runtime.h>

#define N_NODES  100000
#define N_EDGES  1600000
#define N_GRAPHS 2000
#define F_IN     32
#define H        64
#define N_LAYERS 5
#define LN_EPS   1e-5f

#define NXCD     8
#define NPC      (N_NODES / NXCD)    // 12500 nodes per XCD class

#define SCAN_BLK 512
#define SCAN_EPB 2048                                  // 4 elems/thread
#define SCAN_NB  ((N_NODES + SCAN_EPB - 1) / SCAN_EPB) // 49 blocks

typedef unsigned short u16;
typedef int i4 __attribute__((ext_vector_type(4)));    // clang vector type
typedef short s2v __attribute__((ext_vector_type(2))); // 2xbf16 as shorts (dot2 operand)

#if defined(__has_builtin)
#if __has_builtin(__builtin_amdgcn_fdot2_f32_bf16)
#define HAVE_FDOT2 1
#endif
#endif

union i_s2 { int i; s2v v; };

__device__ __forceinline__ float bf2f(u16 v) {
    union { unsigned u; float f; } c; c.u = ((unsigned)v) << 16; return c.f;
}
__device__ __forceinline__ u16 f2bf(float f) {   // round-to-nearest-even
    union { float f; unsigned u; } c; c.f = f;
    return (u16)((c.u + 0x7fffu + ((c.u >> 16) & 1u)) >> 16);
}

// ---------------- CSR build: histogram of dst (int4-vectorized) ----------------
__global__ __launch_bounds__(256) void k_hist(const int* __restrict__ ei,
                                              int* __restrict__ cnt)
{
    const int4* d4 = reinterpret_cast<const int4*>(ei + N_EDGES);
    int i = blockIdx.x * 256 + threadIdx.x;
    int stride = gridDim.x * 256;
    for (int e = i; e < N_EDGES / 4; e += stride) {
        int4 d = d4[e];
        atomicAdd(&cnt[d.x], 1);
        atomicAdd(&cnt[d.y], 1);
        atomicAdd(&cnt[d.z], 1);
        atomicAdd(&cnt[d.w], 1);
    }
}

// ---- CSR build: exclusive scan over PADDED counts (ceil(cnt/4)*4) ----
__global__ __launch_bounds__(SCAN_BLK) void k_scan1(const int* __restrict__ cnt,
                                                    int* __restrict__ rp,
                                                    int* __restrict__ bsum)
{
    __shared__ int s[SCAN_BLK];
    int tid = threadIdx.x;
    int base = blockIdx.x * SCAN_EPB + tid * 4;
    int v0 = (base + 0 < N_NODES) ? ((cnt[base + 0] + 3) & ~3) : 0;
    int v1 = (base + 1 < N_NODES) ? ((cnt[base + 1] + 3) & ~3) : 0;
    int v2 = (base + 2 < N_NODES) ? ((cnt[base + 2] + 3) & ~3) : 0;
    int v3 = (base + 3 < N_NODES) ? ((cnt[base + 3] + 3) & ~3) : 0;
    int tsum = v0 + v1 + v2 + v3;
    s[tid] = tsum;
    __syncthreads();
    for (int off = 1; off < SCAN_BLK; off <<= 1) {
        int t = (tid >= off) ? s[tid - off] : 0;
        __syncthreads();
        s[tid] += t;
        __syncthreads();
    }
    int excl = s[tid] - tsum;
    if (base + 0 < N_NODES) rp[base + 0] = excl;
    if (base + 1 < N_NODES) rp[base + 1] = excl + v0;
    if (base + 2 < N_NODES) rp[base + 2] = excl + v0 + v1;
    if (base + 3 < N_NODES) rp[base + 3] = excl + v0 + v1 + v2;
    if (tid == SCAN_BLK - 1) bsum[blockIdx.x] = s[tid];
}

__global__ void k_scan2(int* __restrict__ bsum, int* __restrict__ rp)
{
    if (threadIdx.x == 0 && blockIdx.x == 0) {
        int acc = 0;
        for (int b = 0; b < SCAN_NB; ++b) { int t = bsum[b]; bsum[b] = acc; acc += t; }
        rp[N_NODES] = acc;   // total padded edge slots
    }
}

__global__ __launch_bounds__(SCAN_BLK) void k_scan3(int* __restrict__ rp,
                                                    const int* __restrict__ bsum,
                                                    int* __restrict__ cursor)
{
    int tid = threadIdx.x, blk = blockIdx.x;
    int add = bsum[blk];
    int base = blk * SCAN_EPB + tid * 4;
    #pragma unroll
    for (int i = 0; i < 4; ++i) {
        int idx = base + i;
        if (idx < N_NODES) { int v = rp[idx] + add; rp[idx] = v; cursor[idx] = v; }
    }
}

// ---- CSR build: zero-fill pad slots (mult=0), XCD-class partitioned ----
// Node n's slot range is 64B-line-aligned (rp padded to 4); class p owns nodes
// [p*NPC,(p+1)*NPC) so each erec line is written by exactly one XCD -> L2 merge.
__global__ __launch_bounds__(256) void k_padfill(const int* __restrict__ rp,
                                                 const int* __restrict__ cnt,
                                                 i4* __restrict__ erec)
{
    int cls = blockIdx.x & (NXCD - 1);
    int vb  = blockIdx.x >> 3, nvb = gridDim.x >> 3;
    int lo = cls * NPC, hi = lo + NPC;
    i4 z = (i4){0, 0, 0, 0};
    for (int n = lo + vb * 256 + threadIdx.x; n < hi; n += nvb * 256) {
        int s = rp[n] + cnt[n], e = rp[n + 1];
        for (int p = s; p < e; ++p) erec[p] = z;
    }
}

// -- CSR build: scatter 16B records {src*16, bf16x2, bf16x2, mult=1.0f} --
// XCD-class partitioned: class p = blockIdx&7 scans all edges, writes only
// dst in its node range -> every erec line written by one XCD -> full-line
// writeback instead of 64B-per-edge partial-line RMW.
__global__ __launch_bounds__(256) void k_scatter(const int* __restrict__ ei,
                                                 const float* __restrict__ ea,
                                                 int* __restrict__ cursor,
                                                 i4* __restrict__ erec)
{
    const float4* a4 = reinterpret_cast<const float4*>(ea);
    const int one = 0x3f800000;   // 1.0f bits
    int cls = blockIdx.x & (NXCD - 1);
    int lo = cls * NPC, hi = lo + NPC;
    int vb  = blockIdx.x >> 3, nvb = gridDim.x >> 3;
    for (int e = vb * 256 + threadIdx.x; e < N_EDGES; e += nvb * 256) {
        int d = ei[N_EDGES + e];
        if (d >= lo && d < hi) {
            int s = ei[e];
            float4 a = a4[e];
            int pos = atomicAdd(&cursor[d], 1);
            erec[pos] = (i4){ s * 16,
                (int)((unsigned)f2bf(a.x) | ((unsigned)f2bf(a.y) << 16)),
                (int)((unsigned)f2bf(a.z) | ((unsigned)f2bf(a.w) << 16)), one };
        }
    }
}

// -------- graph rowptr from sorted batch (boundary detect, no atomics) --------
__global__ __launch_bounds__(256) void k_gptr(const int* __restrict__ batch,
                                              int* __restrict__ gp)
{
    int n = blockIdx.x * 256 + threadIdx.x;
    if (n >= N_NODES) return;
    int b  = batch[n];
    int bp = (n == 0) ? -1 : batch[n - 1];
    for (int g = bp + 1; g <= b; ++g) gp[g] = n;
    if (n == N_NODES - 1)
        for (int g = b + 1; g <= N_GRAPHS; ++g) gp[g] = N_NODES;
}

// ---------------- input projection: h = relu(x @ W_in + b_in) -> bf16 ----------------
__global__ __launch_bounds__(256) void k_input_proj(
        const float* __restrict__ x, const float* __restrict__ Win,
        const float* __restrict__ bin, u16* __restrict__ h)
{
    __shared__ float Ws[F_IN * H];
    __shared__ float bs[H];
    int tid = threadIdx.x;
    for (int i = tid; i < F_IN * H; i += 256) Ws[i] = Win[i];
    if (tid < H) bs[tid] = bin[tid];
    __syncthreads();
    int lane = tid & 63;
    int wid  = tid >> 6;
    for (int n = blockIdx.x * 4 + wid; n < N_NODES; n += gridDim.x * 4) {
        const float* xr = x + (size_t)n * F_IN;
        float acc = bs[lane];
        #pragma unroll
        for (int k = 0; k < F_IN; ++k)
            acc = fmaf(xr[k], Ws[k * H + lane], acc);
        h[(size_t)n * H + lane] = f2bf(fmaxf(acc, 0.f));
    }
}

// ---- fused layer: z = h + sum_in relu(h[src]+e@We+be); h' = relu(mlp(z)) ----
// Phase 1: 16-lane groups, branch-free 4-edge unrolled body (padded lists).
//          ev via v_dot2_f32_bf16 when available (attrs already packed bf16x2).
// Phase 2: tiled 64x64 MLP on LDS z tile.
__global__ __launch_bounds__(256, 8) void k_layer(
        const int* __restrict__ rp, const i4* __restrict__ erec,
        const float* __restrict__ We_l, const float* __restrict__ be_l,
        const float* __restrict__ W1l, const float* __restrict__ b1l,
        const float* __restrict__ W2l, const float* __restrict__ b2l,
        const u16* __restrict__ hin, u16* __restrict__ hout)
{
    __shared__ float zs[64][65];
    int tid  = threadIdx.x;
    int lane = tid & 63, w = tid >> 6;
    int q = lane >> 4, r = lane & 15;     // group q in [0,4), lane-in-group r
    int n0 = blockIdx.x * 64;
    const ushort4* hin4 = reinterpret_cast<const ushort4*>(hin);

    // per-lane: We columns 4r..4r+3 (4 attr rows) + bias
    float4 wr0 = *reinterpret_cast<const float4*>(We_l + 0 * H + r * 4);
    float4 wr1 = *reinterpret_cast<const float4*>(We_l + 1 * H + r * 4);
    float4 wr2 = *reinterpret_cast<const float4*>(We_l + 2 * H + r * 4);
    float4 wr3 = *reinterpret_cast<const float4*>(We_l + 3 * H + r * 4);
    float4 bv  = *reinterpret_cast<const float4*>(be_l + r * 4);

#ifdef HAVE_FDOT2
    // packed bf16 weight pairs: w01[c] = {We[0][4r+c], We[1][4r+c]}, w23[c] = {We[2][..], We[3][..]}
    s2v w01[4], w23[4];
    w01[0] = (s2v){(short)f2bf(wr0.x), (short)f2bf(wr1.x)};
    w01[1] = (s2v){(short)f2bf(wr0.y), (short)f2bf(wr1.y)};
    w01[2] = (s2v){(short)f2bf(wr0.z), (short)f2bf(wr1.z)};
    w01[3] = (s2v){(short)f2bf(wr0.w), (short)f2bf(wr1.w)};
    w23[0] = (s2v){(short)f2bf(wr2.x), (short)f2bf(wr3.x)};
    w23[1] = (s2v){(short)f2bf(wr2.y), (short)f2bf(wr3.y)};
    w23[2] = (s2v){(short)f2bf(wr2.z), (short)f2bf(wr3.z)};
    w23[3] = (s2v){(short)f2bf(wr2.w), (short)f2bf(wr3.w)};
#endif

    for (int t = 0; t < 4; ++t) {
        int row = w * 16 + t * 4 + q;
        int n   = n0 + row;
        float4 acc = make_float4(0.f, 0.f, 0.f, 0.f);
        if (n < N_NODES) {
            ushort4 hs = hin4[(unsigned)n * 16 + r];     // self term (eps=0)
            acc.x = bf2f(hs.x); acc.y = bf2f(hs.y);
            acc.z = bf2f(hs.z); acc.w = bf2f(hs.w);
            int j0 = rp[n], j1 = rp[n + 1];              // padded to multiple of 4
            for (int j = j0; j < j1; j += 4) {
                i4 R[4];
                ushort4 G[4];
                #pragma unroll
                for (int k = 0; k < 4; ++k)
                    R[k] = __builtin_nontemporal_load(&erec[j + k]);
                #pragma unroll
                for (int k = 0; k < 4; ++k)
                    G[k] = hin4[(unsigned)R[k].x + r];   // R.x = src*16
                #pragma unroll
                for (int k = 0; k < 4; ++k) {
                    float mult = __int_as_float(R[k].w);
#ifdef HAVE_FDOT2
                    i_s2 cy, cz; cy.i = R[k].y; cz.i = R[k].z;
                    float e0 = __builtin_amdgcn_fdot2_f32_bf16(cy.v, w01[0],
                               __builtin_amdgcn_fdot2_f32_bf16(cz.v, w23[0], bv.x, false), false);
                    float e1 = __builtin_amdgcn_fdot2_f32_bf16(cy.v, w01[1],
                               __builtin_amdgcn_fdot2_f32_bf16(cz.v, w23[1], bv.y, false), false);
                    float e2 = __builtin_amdgcn_fdot2_f32_bf16(cy.v, w01[2],
                               __builtin_amdgcn_fdot2_f32_bf16(cz.v, w23[2], bv.z, false), false);
                    float e3 = __builtin_amdgcn_fdot2_f32_bf16(cy.v, w01[3],
                               __builtin_amdgcn_fdot2_f32_bf16(cz.v, w23[3], bv.w, false), false);
#else
                    float ax = bf2f((u16)(R[k].y & 0xffff));
                    float ay = bf2f((u16)(((unsigned)R[k].y) >> 16));
                    float az = bf2f((u16)(R[k].z & 0xffff));
                    float aw = bf2f((u16)(((unsigned)R[k].z) >> 16));
                    float e0 = fmaf(ax, wr0.x, fmaf(ay, wr1.x, fmaf(az, wr2.x, fmaf(aw, wr3.x, bv.x))));
                    float e1 = fmaf(ax, wr0.y, fmaf(ay, wr1.y, fmaf(az, wr2.y, fmaf(aw, wr3.y, bv.y))));
                    float e2 = fmaf(ax, wr0.z, fmaf(ay, wr1.z, fmaf(az, wr2.z, fmaf(aw, wr3.z, bv.z))));
                    float e3 = fmaf(ax, wr0.w, fmaf(ay, wr1.w, fmaf(az, wr2.w, fmaf(aw, wr3.w, bv.w))));
#endif
                    acc.x = fmaf(mult, fmaxf(bf2f(G[k].x) + e0, 0.f), acc.x);
                    acc.y = fmaf(mult, fmaxf(bf2f(G[k].y) + e1, 0.f), acc.y);
                    acc.z = fmaf(mult, fmaxf(bf2f(G[k].z) + e2, 0.f), acc.z);
                    acc.w = fmaf(mult, fmaxf(bf2f(G[k].w) + e3, 0.f), acc.w);
                }
            }
        }
        zs[row][r * 4 + 0] = acc.x;
        zs[row][r * 4 + 1] = acc.y;
        zs[row][r * 4 + 2] = acc.z;
        zs[row][r * 4 + 3] = acc.w;
    }
    __syncthreads();

    // phase 2: MLP on the 64x64 tile
    int tr = (tid >> 4) * 4, tc = (tid & 15) * 4;
    float a1[4][4];
    #pragma unroll
    for (int i = 0; i < 4; ++i)
        #pragma unroll
        for (int j = 0; j < 4; ++j) a1[i][j] = b1l[tc + j];
    #pragma unroll 8
    for (int k = 0; k < H; ++k) {
        float4 wv = *reinterpret_cast<const float4*>(&W1l[k * H + tc]);
        #pragma unroll
        for (int i = 0; i < 4; ++i) {
            float zr = zs[tr + i][k];
            a1[i][0] = fmaf(zr, wv.x, a1[i][0]);
            a1[i][1] = fmaf(zr, wv.y, a1[i][1]);
            a1[i][2] = fmaf(zr, wv.z, a1[i][2]);
            a1[i][3] = fmaf(zr, wv.w, a1[i][3]);
        }
    }
    __syncthreads();
    #pragma unroll
    for (int i = 0; i < 4; ++i)
        #pragma unroll
        for (int j = 0; j < 4; ++j) zs[tr + i][tc + j] = fmaxf(a1[i][j], 0.f);
    __syncthreads();

    float a2[4][4];
    #pragma unroll
    for (int i = 0; i < 4; ++i)
        #pragma unroll
        for (int j = 0; j < 4; ++j) a2[i][j] = b2l[tc + j];
    #pragma unroll 8
    for (int k = 0; k < H; ++k) {
        float4 wv = *reinterpret_cast<const float4*>(&W2l[k * H + tc]);
        #pragma unroll
        for (int i = 0; i < 4; ++i) {
            float zr = zs[tr + i][k];
            a2[i][0] = fmaf(zr, wv.x, a2[i][0]);
            a2[i][1] = fmaf(zr, wv.y, a2[i][1]);
            a2[i][2] = fmaf(zr, wv.z, a2[i][2]);
            a2[i][3] = fmaf(zr, wv.w, a2[i][3]);
        }
    }
    #pragma unroll
    for (int i = 0; i < 4; ++i) {
        int n = n0 + tr + i;
        if (n < N_NODES) {
            ushort4 o;
            o.x = f2bf(fmaxf(a2[i][0], 0.f));
            o.y = f2bf(fmaxf(a2[i][1], 0.f));
            o.z = f2bf(fmaxf(a2[i][2], 0.f));
            o.w = f2bf(fmaxf(a2[i][3], 0.f));
            *reinterpret_cast<ushort4*>(&hout[(size_t)n * H + tc]) = o;
        }
    }
}

// ------- fused pool + LN + head: one wave per graph, 4-deep accumulation -------
__global__ __launch_bounds__(64) void k_poolfinal(
        const u16* __restrict__ hb, const int* __restrict__ gp,
        const float* __restrict__ Wout, const float* __restrict__ bout,
        float* __restrict__ out)
{
    int g = blockIdx.x, lane = threadIdx.x;
    int a = gp[g], b = gp[g + 1];
    float s0 = 0.f, s1 = 0.f, s2a = 0.f, s3 = 0.f;
    int n = a;
    for (; n + 3 < b; n += 4) {
        s0  += bf2f(hb[(size_t)n * H + lane]);
        s1  += bf2f(hb[(size_t)(n + 1) * H + lane]);
        s2a += bf2f(hb[(size_t)(n + 2) * H + lane]);
        s3  += bf2f(hb[(size_t)(n + 3) * H + lane]);
    }
    for (; n < b; ++n) s0 += bf2f(hb[(size_t)n * H + lane]);
    float v = ((s0 + s1) + (s2a + s3)) / fmaxf((float)(b - a), 1.f);
    float t = v;
    #pragma unroll
    for (int off = 32; off; off >>= 1) t += __shfl_xor(t, off);
    float mu = t * (1.0f / H);
    float d  = v - mu;
    float s2 = d * d;
    #pragma unroll
    for (int off = 32; off; off >>= 1) s2 += __shfl_xor(s2, off);
    float var = s2 * (1.0f / H);
    float y = d * rsqrtf(var + LN_EPS);
    float p = y * Wout[lane];
    #pragma unroll
    for (int off = 32; off; off >>= 1) p += __shfl_xor(p, off);
    if (lane == 0) out[g] = p + bout[0];
}

extern "C" void kernel_launch(void* const* d_in, const int* in_sizes, int n_in,
                              void* d_out, int out_size, void* d_ws, size_t ws_size,
                              hipStream_t stream)
{
    const float* x     = (const float*)d_in[0];
    const int*   ei    = (const int*)  d_in[1];
    const float* ea    = (const float*)d_in[2];
    const int*   batch = (const int*)  d_in[3];
    const float* Win   = (const float*)d_in[4];
    const float* bin   = (const float*)d_in[5];
    const float* We    = (const float*)d_in[6];
    const float* be    = (const float*)d_in[7];
    const float* W1    = (const float*)d_in[8];
    const float* b1    = (const float*)d_in[9];
    const float* W2    = (const float*)d_in[10];
    const float* b2    = (const float*)d_in[11];
    const float* Wout  = (const float*)d_in[12];
    const float* bout  = (const float*)d_in[13];
    float* out = (float*)d_out;

    char* ws = (char*)d_ws;
    size_t off = 0;
    auto alloc = [&](size_t bytes) -> char* {
        char* p = ws + off;
        off += (bytes + 255) & ~(size_t)255;
        return p;
    };
    const size_t HBH   = (size_t)N_NODES * H * sizeof(u16);              // 12.8 MB
    const size_t NEPAD = (size_t)N_EDGES + 3 * (size_t)N_NODES + 64;     // padded capacity + tail slack
    u16*  h0     = (u16*) alloc(HBH);
    u16*  h1     = (u16*) alloc(HBH);
    i4*   erec   = (i4*)  alloc(NEPAD * sizeof(i4));                     // ~30.4 MB
    int*  cnt    = (int*) alloc((size_t)N_NODES * sizeof(int));
    int*  rp     = (int*) alloc((size_t)(N_NODES + 1) * sizeof(int));
    int*  cursor = (int*) alloc((size_t)N_NODES * sizeof(int));
    int*  bsum   = (int*) alloc((size_t)SCAN_NB * sizeof(int));
    int*  gp     = (int*) alloc((size_t)(N_GRAPHS + 1) * sizeof(int));

    // ---- CSR build (dst-sorted padded edge records, attrs bf16, src pre-scaled) ----
    (void)hipMemsetAsync(cnt, 0, (size_t)N_NODES * sizeof(int), stream);
    k_hist<<<2048, 256, 0, stream>>>(ei, cnt);
    k_scan1<<<SCAN_NB, SCAN_BLK, 0, stream>>>(cnt, rp, bsum);
    k_scan2<<<1, 64, 0, stream>>>(bsum, rp);
    k_scan3<<<SCAN_NB, SCAN_BLK, 0, stream>>>(rp, bsum, cursor);
    k_padfill<<<8 * 49, 256, 0, stream>>>(rp, cnt, erec);
    k_scatter<<<4096, 256, 0, stream>>>(ei, ea, cursor, erec);
    k_gptr<<<(N_NODES + 255) / 256, 256, 0, stream>>>(batch, gp);

    // ---- network ----
    k_input_proj<<<1024, 256, 0, stream>>>(x, Win, bin, h0);
    u16* cur = h0;
    u16* nxt = h1;
    const int NBLK = (N_NODES + 63) / 64;
    for (int l = 0; l < N_LAYERS; ++l) {
        k_layer<<<NBLK, 256, 0, stream>>>(rp, erec,
                We + (size_t)l * 4 * H, be + (size_t)l * H,
                W1 + (size_t)l * H * H, b1 + (size_t)l * H,
                W2 + (size_t)l * H * H, b2 + (size_t)l * H,
                cur, nxt);
        u16* t = cur; cur = nxt; nxt = t;
    }

    k_poolfinal<<<N_GRAPHS, 64, 0, stream>>>(cur, gp, Wout, bout, out);
}